// Round 5
// baseline (284.373 us; speedup 1.0000x reference)
//
#include <hip/hip_runtime.h>
#include <math.h>

#define DIM 512
#define NB 256
#define KMAX 16   // Taylor terms (powers A^1..A^16)

using bf16x8 = __attribute__((ext_vector_type(8))) short;
using f32x4  = __attribute__((ext_vector_type(4))) float;
using float4v = __attribute__((ext_vector_type(4))) float;

__device__ __forceinline__ unsigned short f2b(float f) {
    union { float f; unsigned int u; } v; v.f = f;
    unsigned int r = v.u + 0x7fffu + ((v.u >> 16) & 1u);
    return (unsigned short)(r >> 16);
}
__device__ __forceinline__ float b2f(unsigned short u) {
    union { unsigned int u; float f; } v; v.u = ((unsigned int)u) << 16;
    return v.f;
}

// ---------------------------------------------------------------------------
// Batched bf16 MFMA GEMM (same core as round 4; see comments there).
// ---------------------------------------------------------------------------
struct GemmDesc {
    const unsigned short* X;
    const unsigned short* W;
    const float* bias;
    float* Cf;
    unsigned short* Cb;
    unsigned short* Ct;
    int M, N, K, ldX, ldC, tr_row0;
};
struct GemmArgs { GemmDesc d[4]; };

__global__ __launch_bounds__(256) void gemm_mfma(GemmArgs args)
{
    GemmDesc de = args.d[blockIdx.y];
    int tn = de.N >> 6;
    int tiles = (de.M >> 6) * tn;
    int t = blockIdx.x;
    if (t >= tiles) return;
    int m0 = (t / tn) << 6;
    int n0 = (t % tn) << 6;

    __shared__ unsigned short lsA[2][4096];
    __shared__ unsigned short lsB[2][4096];

    int tid = threadIdx.x;
    int w = tid >> 6;
    int l = tid & 63;
    int nkt = de.K >> 6;

    int srow = w * 16 + (l >> 2);
    int schk = l & 3;
    const unsigned short* gA = de.X + (size_t)(m0 + srow) * de.ldX + schk * 8;
    const unsigned short* gB = de.W + (size_t)(n0 + srow) * de.K  + schk * 8;
    unsigned short* lA = &lsA[0][(w * 64 + l) * 8];
    unsigned short* lB = &lsB[0][(w * 64 + l) * 8];

#define STAGE(bufi, kt)                                                          \
    do {                                                                         \
        __builtin_amdgcn_global_load_lds(                                        \
            (const __attribute__((address_space(1))) unsigned int*)(gA + (size_t)(kt) * 64), \
            (__attribute__((address_space(3))) unsigned int*)(lA + (bufi) * 4096), 16, 0, 0); \
        __builtin_amdgcn_global_load_lds(                                        \
            (const __attribute__((address_space(1))) unsigned int*)(gA + (size_t)(kt) * 64 + 32), \
            (__attribute__((address_space(3))) unsigned int*)(lA + (bufi) * 4096 + 2048), 16, 0, 0); \
        __builtin_amdgcn_global_load_lds(                                        \
            (const __attribute__((address_space(1))) unsigned int*)(gB + (size_t)(kt) * 64), \
            (__attribute__((address_space(3))) unsigned int*)(lB + (bufi) * 4096), 16, 0, 0); \
        __builtin_amdgcn_global_load_lds(                                        \
            (const __attribute__((address_space(1))) unsigned int*)(gB + (size_t)(kt) * 64 + 32), \
            (__attribute__((address_space(3))) unsigned int*)(lB + (bufi) * 4096 + 2048), 16, 0, 0); \
    } while (0)

    int mbase = (w >> 1) * 32;
    int nbase = (w & 1) * 32;

    f32x4 acc[2][2];
    #pragma unroll
    for (int i = 0; i < 2; ++i)
        #pragma unroll
        for (int j = 0; j < 2; ++j)
            acc[i][j] = (f32x4){0.f, 0.f, 0.f, 0.f};

    int kg = l >> 4;
    int fr = l & 15;
    int aslot = (mbase * 4 + fr * 4 + kg) * 8;
    int bslot = (nbase * 4 + fr * 4 + kg) * 8;

    STAGE(0, 0);

    for (int kt = 0; kt < nkt; ++kt) {
        __syncthreads();
        if (kt + 1 < nkt) STAGE((kt + 1) & 1, kt + 1);

        const unsigned short* bufA = &lsA[kt & 1][0];
        const unsigned short* bufB = &lsB[kt & 1][0];
        #pragma unroll
        for (int h = 0; h < 2; ++h) {
            bf16x8 a0 = *(const bf16x8*)(bufA + h * 2048 + aslot);
            bf16x8 a1 = *(const bf16x8*)(bufA + h * 2048 + aslot + 512);
            bf16x8 b0 = *(const bf16x8*)(bufB + h * 2048 + bslot);
            bf16x8 b1 = *(const bf16x8*)(bufB + h * 2048 + bslot + 512);
            acc[0][0] = __builtin_amdgcn_mfma_f32_16x16x32_bf16(a0, b0, acc[0][0], 0, 0, 0);
            acc[0][1] = __builtin_amdgcn_mfma_f32_16x16x32_bf16(a0, b1, acc[0][1], 0, 0, 0);
            acc[1][0] = __builtin_amdgcn_mfma_f32_16x16x32_bf16(a1, b0, acc[1][0], 0, 0, 0);
            acc[1][1] = __builtin_amdgcn_mfma_f32_16x16x32_bf16(a1, b1, acc[1][1], 0, 0, 0);
        }
    }

    #pragma unroll
    for (int mi = 0; mi < 2; ++mi) {
        #pragma unroll
        for (int ni = 0; ni < 2; ++ni) {
            int col = n0 + nbase + ni * 16 + fr;
            float bv = de.bias ? de.bias[col] : 0.f;
            #pragma unroll
            for (int r = 0; r < 4; ++r) {
                int row = m0 + mbase + mi * 16 + (l >> 4) * 4 + r;
                float v = acc[mi][ni][r] + bv;
                if (de.Cf) de.Cf[(size_t)row * de.ldC + col] = v;
                else       de.Cb[(size_t)row * de.ldC + col] = f2b(v);
                if (de.Ct && row >= de.tr_row0)
                    de.Ct[(size_t)col * 512 + (row - de.tr_row0)] = f2b(v);
            }
        }
    }
#undef STAGE
}

// ---------------------------------------------------------------------------
// Fused prep: fp32->bf16 converts (linear + strided), 2 LDS-tiled transposes
// (A^T, aout_w^T), and bprime[i] = proj_b[i] + sum_n proj_w[i,512+n]*aout_b[n].
// Grid: 1544 blocks x 256.
// ---------------------------------------------------------------------------
struct PrepArgs {
    const float* lin_s[7]; unsigned short* lin_d[7];
    int lin_n4[7]; int lin_dRL[7]; int lin_sRL[7]; int lin_sOff[7];
    const float* A; unsigned short* ATb;
    const float* aout_w; unsigned short* aout_wT;
    const float* proj_w; const float* proj_b; const float* aout_b; float* bprime;
};
__global__ __launch_bounds__(256) void prep_kernel(PrepArgs a)
{
    __shared__ float tile[32][33];
    int bid = blockIdx.x, tid = threadIdx.x;
    if (bid < 1024) {
        int gstride = 1024 * 256;
        int g0 = bid * 256 + tid;
        for (int seg = 0; seg < 7; ++seg) {
            int n4 = a.lin_n4[seg];
            const float* s = a.lin_s[seg];
            unsigned short* d = a.lin_d[seg];
            int dRL = a.lin_dRL[seg], sRL = a.lin_sRL[seg], off = a.lin_sOff[seg];
            if (dRL == sRL && off == 0) {
                for (int i = g0; i < n4; i += gstride) {
                    float4v v = ((const float4v*)s)[i];
                    d[i*4+0] = f2b(v.x); d[i*4+1] = f2b(v.y);
                    d[i*4+2] = f2b(v.z); d[i*4+3] = f2b(v.w);
                }
            } else {
                for (int i = g0; i < n4; i += gstride) {
                    int r = i / dRL, c = i - r * dRL;
                    float4v v = *(const float4v*)(s + ((size_t)r * sRL + off + c) * 4);
                    unsigned short* dd = d + ((size_t)r * dRL + c) * 4;
                    dd[0] = f2b(v.x); dd[1] = f2b(v.y); dd[2] = f2b(v.z); dd[3] = f2b(v.w);
                }
            }
        }
    } else if (bid < 1536) {
        int t = bid - 1024;
        const float* src = (t < 256) ? a.A : a.aout_w;
        unsigned short* dst = (t < 256) ? a.ATb : a.aout_wT;
        int tt = t & 255;
        int bx = tt & 15, by = tt >> 4;
        int tx = tid & 31, ty = tid >> 5;   // ty 0..7
        #pragma unroll
        for (int i = 0; i < 32; i += 8)
            tile[ty + i][tx] = src[(size_t)(by * 32 + ty + i) * 512 + bx * 32 + tx];
        __syncthreads();
        #pragma unroll
        for (int i = 0; i < 32; i += 8)
            dst[(size_t)(bx * 32 + ty + i) * 512 + by * 32 + tx] = f2b(tile[tx][ty + i]);
    } else {
        int gw = (bid - 1536) * 4 + (tid >> 6);
        int lane = tid & 63;
        for (int i = gw; i < 512; i += 32) {
            float acc = 0.f;
            for (int n = lane; n < 512; n += 64)
                acc += a.proj_w[(size_t)i * 2560 + 512 + n] * a.aout_b[n];
            #pragma unroll
            for (int off = 32; off > 0; off >>= 1) acc += __shfl_down(acc, off);
            if (lane == 0) a.bprime[i] = a.proj_b[i] + acc;
        }
    }
}

// ---------------------------------------------------------------------------
// build LSTM concatenated weights Wcat_s = [wih_s | whh_s] (2048 x 1024) bf16
// and Xcat_s = [x | lstm_h_s] (256 x 1024) bf16
// ---------------------------------------------------------------------------
__global__ void build_lstm_cat(const float* __restrict__ wih, const float* __restrict__ whh,
                               const float* __restrict__ x, const float* __restrict__ lh,
                               unsigned short* __restrict__ Wcat, unsigned short* __restrict__ Xcat)
{
    int stride = gridDim.x * blockDim.x;
    const int W4 = 3 * 2048 * 256;
    const int X4 = 3 * 256 * 256;
    for (int g = blockIdx.x * blockDim.x + threadIdx.x; g < W4; g += stride) {
        int s = g / 524288;
        int rr = g - s * 524288;
        int r = rr >> 8;
        int c = (rr & 255) * 4;
        const float* src = (c < 512) ? (wih + (size_t)s * 1048576 + (size_t)r * 512 + c)
                                     : (whh + (size_t)s * 1048576 + (size_t)r * 512 + (c - 512));
        float4v v = *(const float4v*)src;
        unsigned short* dst = Wcat + (size_t)s * 2097152 + (size_t)r * 1024 + c;
        dst[0] = f2b(v.x); dst[1] = f2b(v.y); dst[2] = f2b(v.z); dst[3] = f2b(v.w);
    }
    for (int g = blockIdx.x * blockDim.x + threadIdx.x; g < X4; g += stride) {
        int s = g / 65536;
        int rr = g - s * 65536;
        int b = rr >> 8;
        int c = (rr & 255) * 4;
        const float* src = (c < 512) ? (x + (size_t)b * 512 + c)
                                     : (lh + (size_t)s * 131072 + (size_t)b * 512 + (c - 512));
        float4v v = *(const float4v*)src;
        unsigned short* dst = Xcat + (size_t)s * 262144 + (size_t)b * 1024 + c;
        dst[0] = f2b(v.x); dst[1] = f2b(v.y); dst[2] = f2b(v.z); dst[3] = f2b(v.w);
    }
}

// ---------------------------------------------------------------------------
__device__ __forceinline__ void block_reduce2(float& s, float& q, float* sb1, float* sb2)
{
    int tid = threadIdx.x;
    #pragma unroll
    for (int off = 32; off > 0; off >>= 1) {
        s += __shfl_down(s, off);
        q += __shfl_down(q, off);
    }
    if ((tid & 63) == 0) { sb1[tid >> 6] = s; sb2[tid >> 6] = q; }
    __syncthreads();
    s = sb1[0] + sb1[1] + sb1[2] + sb1[3];
    q = sb2[0] + sb2[1] + sb2[2] + sb2[3];
    __syncthreads();
}

__global__ __launch_bounds__(256) void ln_gelu_delta(
    const float* __restrict__ pre, const float* __restrict__ g,
    const float* __restrict__ beta, const float* __restrict__ w2,
    const float* __restrict__ b2, float* __restrict__ delta,
    float* __restrict__ coeff)
{
    __shared__ float sb1[4], sb2[4];
    int b = blockIdx.x, tid = threadIdx.x;
    int i0 = tid, i1 = tid + 256;
    float x0 = pre[(size_t)b * DIM + i0];
    float x1 = pre[(size_t)b * DIM + i1];
    float s = x0 + x1, q = x0 * x0 + x1 * x1;
    block_reduce2(s, q, sb1, sb2);
    float mean = s * (1.f / DIM);
    float var  = q * (1.f / DIM) - mean * mean;
    float inv  = rsqrtf(var + 1e-5f);
    float y0 = (x0 - mean) * inv * g[i0] + beta[i0];
    float y1 = (x1 - mean) * inv * g[i1] + beta[i1];
    float h0 = 0.5f * y0 * (1.f + erff(y0 * 0.70710678118654752f));
    float h1 = 0.5f * y1 * (1.f + erff(y1 * 0.70710678118654752f));
    float p = h0 * w2[i0] + h1 * w2[i1];
    float dummy = 0.f;
    block_reduce2(p, dummy, sb1, sb2);
    if (tid == 0) {
        float z = p + b2[0];
        float d = (z > 20.f) ? z : log1pf(expf(z));
        delta[b] = d;
        float c = 1.f;
        coeff[b] = 1.f;
        for (int k = 1; k <= KMAX; ++k) { c *= d / (float)k; coeff[k * 256 + b] = c; }
    }
}

// ---------------------------------------------------------------------------
// Fused pointwise: Taylor-accum (first 131072 idx) + LSTM cell (rest).
// ---------------------------------------------------------------------------
__global__ void pointwise_fused(
    const float* __restrict__ Tm, const float* __restrict__ coeff,
    const float* __restrict__ h_prev, const float* __restrict__ delta,
    const float* __restrict__ Bx, float* __restrict__ hssm,
    unsigned short* __restrict__ combb,
    const float* __restrict__ gates, const float* __restrict__ bih,
    const float* __restrict__ bhh, const float* __restrict__ cin,
    const float* __restrict__ decays,
    float* __restrict__ hout, float* __restrict__ cout)
{
    int idx = blockIdx.x * 256 + threadIdx.x;   // 0..524287
    if (idx < 131072) {
        int b = idx >> 9, i = idx & 511;
        const float* Tr = Tm + (size_t)b * (KMAX * DIM) + i;
        float a = h_prev[idx];
        #pragma unroll
        for (int k = 1; k <= KMAX; ++k)
            a += coeff[k * 256 + b] * Tr[(size_t)(k - 1) * DIM];
        float h = a + delta[b] * Bx[idx];
        hssm[idx] = h;
        combb[(size_t)b * 2560 + i] = f2b(h);
    } else {
        int idx2 = idx - 131072;                // 0..393215
        int s = idx2 / (NB * DIM);
        int r = idx2 - s * (NB * DIM);
        int b = r >> 9, d = r & 511;
        const float* gr = gates + (size_t)s * 524288 + (size_t)b * 2048;
        const float* bi = bih + s * 2048;
        const float* bh = bhh + s * 2048;
        float gi = gr[d]        + bi[d]        + bh[d];
        float gf = gr[512 + d]  + bi[512 + d]  + bh[512 + d];
        float gg = gr[1024 + d] + bi[1024 + d] + bh[1024 + d];
        float go = gr[1536 + d] + bi[1536 + d] + bh[1536 + d];
        float ig = 1.f / (1.f + expf(-gi));
        float fg = 1.f / (1.f + expf(-gf));
        float g_ = tanhf(gg);
        float og = 1.f / (1.f + expf(-go));
        float c  = cin[idx2];
        float craw = fg * c + ig * g_;
        float hn = og * tanhf(craw);
        float dec = decays[s];
        hout[idx2] = hn;
        cout[idx2] = dec * c + (1.f - dec) * craw;
        combb[(size_t)b * 2560 + 1024 + s * 512 + d] = f2b(hn);
    }
}

// ---------------------------------------------------------------------------
// Attention; writes ctx (bf16) directly into combb cols 512..1023.
// ---------------------------------------------------------------------------
__global__ __launch_bounds__(64) void attn_kernel(
    const unsigned short* __restrict__ qb, const unsigned short* __restrict__ kvb,
    unsigned short* __restrict__ combb)
{
    int bh = blockIdx.x;
    int b = bh >> 3, h = bh & 7;
    int e = threadIdx.x;
    int col = h * 64 + e;
    float qe = b2f(qb[(size_t)b * 512 + col]);
    float p0 = qe * b2f(kvb[0 * 262144 + (size_t)b * 1024 + col]);
    float p1 = qe * b2f(kvb[1 * 262144 + (size_t)b * 1024 + col]);
    float p2 = qe * b2f(kvb[2 * 262144 + (size_t)b * 1024 + col]);
    #pragma unroll
    for (int off = 32; off > 0; off >>= 1) {
        p0 += __shfl_xor(p0, off);
        p1 += __shfl_xor(p1, off);
        p2 += __shfl_xor(p2, off);
    }
    const float scale = 0.125f;
    p0 *= scale; p1 *= scale; p2 *= scale;
    float m = fmaxf(p0, fmaxf(p1, p2));
    float w0 = expf(p0 - m), w1 = expf(p1 - m), w2 = expf(p2 - m);
    float invs = 1.f / (w0 + w1 + w2);
    float v0 = b2f(kvb[0 * 262144 + (size_t)b * 1024 + 512 + col]);
    float v1 = b2f(kvb[1 * 262144 + (size_t)b * 1024 + 512 + col]);
    float v2 = b2f(kvb[2 * 262144 + (size_t)b * 1024 + 512 + col]);
    combb[(size_t)b * 2560 + 512 + col] = f2b((w0 * v0 + w1 * v1 + w2 * v2) * invs);
}

// ---------------------------------------------------------------------------
__global__ __launch_bounds__(256) void layernorm_k(
    const float* __restrict__ in, const float* __restrict__ g,
    const float* __restrict__ beta, float* __restrict__ outp)
{
    __shared__ float sb1[4], sb2[4];
    int b = blockIdx.x, tid = threadIdx.x;
    int i0 = tid, i1 = tid + 256;
    float x0 = in[(size_t)b * DIM + i0];
    float x1 = in[(size_t)b * DIM + i1];
    float s = x0 + x1, q = x0 * x0 + x1 * x1;
    block_reduce2(s, q, sb1, sb2);
    float mean = s * (1.f / DIM);
    float var  = q * (1.f / DIM) - mean * mean;
    float inv  = rsqrtf(var + 1e-5f);
    outp[(size_t)b * DIM + i0] = (x0 - mean) * inv * g[i0] + beta[i0];
    outp[(size_t)b * DIM + i1] = (x1 - mean) * inv * g[i1] + beta[i1];
}

// ---------------------------------------------------------------------------
extern "C" void kernel_launch(void* const* d_in, const int* in_sizes, int n_in,
                              void* d_out, int out_size, void* d_ws, size_t ws_size,
                              hipStream_t stream)
{
    const float* x        = (const float*)d_in[0];
    const float* h_prev   = (const float*)d_in[1];
    const float* lstm_h   = (const float*)d_in[2];
    const float* lstm_c   = (const float*)d_in[3];
    const float* A        = (const float*)d_in[4];
    const float* Bm       = (const float*)d_in[5];
    const float* dn_w1    = (const float*)d_in[6];
    const float* dn_b1    = (const float*)d_in[7];
    const float* dn_g     = (const float*)d_in[8];
    const float* dn_beta  = (const float*)d_in[9];
    const float* dn_w2    = (const float*)d_in[10];
    const float* dn_b2    = (const float*)d_in[11];
    const float* wih      = (const float*)d_in[12];
    const float* whh      = (const float*)d_in[13];
    const float* bih      = (const float*)d_in[14];
    const float* bhh      = (const float*)d_in[15];
    const float* decays   = (const float*)d_in[16];
    const float* ain_w    = (const float*)d_in[17];
    const float* ain_b    = (const float*)d_in[18];
    const float* aout_w   = (const float*)d_in[19];
    const float* aout_b   = (const float*)d_in[20];
    const float* proj_w   = (const float*)d_in[21];
    const float* proj_b   = (const float*)d_in[22];
    const float* proj_g   = (const float*)d_in[23];
    const float* proj_bt  = (const float*)d_in[24];

    float* out  = (float*)d_out;
    float* hssm = out + 131072;
    float* hnew = out + 262144;
    float* cnew = out + 655360;

    // ---- workspace (bf16 section) ----
    unsigned short* us = (unsigned short*)d_ws;
    unsigned short* hpb     = us;                  // 131072
    unsigned short* ATb     = us + 131072;         // 262144
    unsigned short* dn_w1b  = us + 393216;         // 262144
    unsigned short* Bmb     = us + 655360;         // 262144
    unsigned short* ain_wb  = us + 917504;         // 786432
    unsigned short* proj_wb = us + 1703936;        // 1310720 (512 x 2560)
    unsigned short* P2b     = us + 3014656;        // 262144 (proj_w block 2)
    unsigned short* aout_wT = us + 3276800;        // 262144
    unsigned short* Pw      = us + 3538944;        // 16*262144 = 4194304 [A^1..A^16]
    unsigned short* Qa      = us + 7733248;        // 262144
    unsigned short* Qb      = us + 7995392;        // 262144
    unsigned short* Wcat    = us + 8257536;        // 6291456
    unsigned short* Xcat    = us + 14548992;       // 786432
    unsigned short* combb   = us + 15335424;       // 655360 (256 x 2560)
    unsigned short* qb      = us + 15990784;       // 131072
    unsigned short* kvb     = us + 16121856;       // 786432
    // ---- fp32 section ----
    float* fbase  = (float*)(us + 16908288);
    float* pre1   = fbase;                         // 131072 (reused as projout)
    float* delta  = fbase + 131072;                // 256
    float* coeff  = fbase + 131328;                // 17*256 -> 4352
    float* Bx     = fbase + 135680;                // 131072
    float* bprime = fbase + 266752;                // 512
    float* Tm     = fbase + 267264;                // 256*8192 = 2097152
    float* gates  = fbase + 2364416;               // 1572864
    float* projout = pre1;

    // ---- 1. prep (all converts + transposes + bprime) ----
    PrepArgs pa;
    pa.lin_s[0] = h_prev; pa.lin_d[0] = hpb;     pa.lin_n4[0] = 32768;  pa.lin_dRL[0]=1;   pa.lin_sRL[0]=1;   pa.lin_sOff[0]=0;
    pa.lin_s[1] = A;      pa.lin_d[1] = Pw;      pa.lin_n4[1] = 65536;  pa.lin_dRL[1]=1;   pa.lin_sRL[1]=1;   pa.lin_sOff[1]=0;
    pa.lin_s[2] = dn_w1;  pa.lin_d[2] = dn_w1b;  pa.lin_n4[2] = 65536;  pa.lin_dRL[2]=1;   pa.lin_sRL[2]=1;   pa.lin_sOff[2]=0;
    pa.lin_s[3] = Bm;     pa.lin_d[3] = Bmb;     pa.lin_n4[3] = 65536;  pa.lin_dRL[3]=1;   pa.lin_sRL[3]=1;   pa.lin_sOff[3]=0;
    pa.lin_s[4] = ain_w;  pa.lin_d[4] = ain_wb;  pa.lin_n4[4] = 196608; pa.lin_dRL[4]=1;   pa.lin_sRL[4]=1;   pa.lin_sOff[4]=0;
    pa.lin_s[5] = proj_w; pa.lin_d[5] = proj_wb; pa.lin_n4[5] = 327680; pa.lin_dRL[5]=1;   pa.lin_sRL[5]=1;   pa.lin_sOff[5]=0;
    pa.lin_s[6] = proj_w; pa.lin_d[6] = P2b;     pa.lin_n4[6] = 65536;  pa.lin_dRL[6]=128; pa.lin_sRL[6]=640; pa.lin_sOff[6]=128;
    pa.A = A; pa.ATb = ATb; pa.aout_w = aout_w; pa.aout_wT = aout_wT;
    pa.proj_w = proj_w; pa.proj_b = proj_b; pa.aout_b = aout_b; pa.bprime = bprime;
    prep_kernel<<<1544, 256, 0, stream>>>(pa);
    build_lstm_cat<<<2048, 256, 0, stream>>>(wih, whh, x, lstm_h, Wcat, Xcat);

    GemmArgs ga;
    // ---- 2. batch1: dense1, Bx, M2 = P2 . aout_w -> proj_wb block 2 ----
    ga.d[0] = { Xcat, dn_w1b, dn_b1, pre1, nullptr, nullptr, 256, 512, 512, 1024, 512, 0 };
    ga.d[1] = { Xcat, Bmb,    nullptr, Bx,  nullptr, nullptr, 256, 512, 512, 1024, 512, 0 };
    ga.d[2] = { P2b,  aout_wT, nullptr, nullptr, proj_wb + 512, nullptr, 512, 512, 512, 512, 2560, 0 };
    ga.d[3] = ga.d[0];
    gemm_mfma<<<dim3(64, 3), 256, 0, stream>>>(ga);
    ln_gelu_delta<<<256, 256, 0, stream>>>(pre1, dn_g, dn_beta, dn_w2, dn_b2, delta, coeff);

    // ---- 3. power chain (4 steps): A^2; [A^3,A^4]; [A^5..A^8]; [A^9..A^16] ----
    ga.d[0] = { Pw, ATb, nullptr, nullptr, Pw + 1*262144, Qa, 512, 512, 512, 512, 512, 0 };
    gemm_mfma<<<dim3(64, 1), 256, 0, stream>>>(ga);
    ga.d[0] = { Pw, Qa, nullptr, nullptr, Pw + 2*262144, Qb, 1024, 512, 512, 512, 512, 512 };
    gemm_mfma<<<dim3(128, 1), 256, 0, stream>>>(ga);
    ga.d[0] = { Pw, Qb, nullptr, nullptr, Pw + 4*262144, Qa, 2048, 512, 512, 512, 512, 1536 };
    gemm_mfma<<<dim3(256, 1), 256, 0, stream>>>(ga);
    ga.d[0] = { Pw, Qa, nullptr, nullptr, Pw + 8*262144, nullptr, 4096, 512, 512, 512, 512, 0 };
    gemm_mfma<<<dim3(512, 1), 256, 0, stream>>>(ga);

    // ---- 4. batch2: Taylor (N=8192) + LSTM x3 (independent) ----
    ga.d[0] = { hpb, Pw, nullptr, Tm, nullptr, nullptr, 256, KMAX*512, 512, 512, KMAX*512, 0 };
    for (int s = 0; s < 3; ++s)
        ga.d[1 + s] = { Xcat + (size_t)s * 262144, Wcat + (size_t)s * 2097152, nullptr,
                        gates + (size_t)s * 524288, nullptr, nullptr, 256, 2048, 1024, 1024, 2048, 0 };
    gemm_mfma<<<dim3(512, 4), 256, 0, stream>>>(ga);

    // ---- 5. fused pointwise: taylor accum + lstm cell ----
    pointwise_fused<<<2048, 256, 0, stream>>>(Tm, coeff, h_prev, delta, Bx, hssm, combb,
                                              gates, bih, bhh, lstm_c, decays, hnew, cnew);

    // ---- 6. attention qkv (batched) + softmax (ctx -> combb) ----
    ga.d[0] = { combb, ain_wb, ain_b, nullptr, qb, nullptr, 256, 512, 512, 2560, 512, 0 };
    for (int s = 0; s < 3; ++s)
        ga.d[1 + s] = { combb + 1024 + (size_t)s * 512, ain_wb + 262144, ain_b + 512,
                        nullptr, kvb + (size_t)s * 262144, nullptr, 256, 1024, 512, 2560, 1024, 0 };
    gemm_mfma<<<dim3(64, 4), 256, 0, stream>>>(ga);
    attn_kernel<<<2048, 64, 0, stream>>>(qb, kvb, combb);

    // ---- 7. projection (K=2560, M2-fused, bias=bprime) + final LN ----
    ga.d[0] = { combb, proj_wb, bprime, projout, nullptr, nullptr, 256, 512, 2560, 2560, 512, 0 };
    gemm_mfma<<<dim3(32, 1), 256, 0, stream>>>(ga);
    layernorm_k<<<256, 256, 0, stream>>>(projout, proj_g, proj_bt, out);
}

// Round 7
// 234.607 us; speedup vs baseline: 1.2121x; 1.2121x over previous
//
#include <hip/hip_runtime.h>
#include <math.h>

#define DIM 512
#define NB 256
#define KMAX 16   // Taylor terms (powers A^1..A^16)

using bf16x8 = __attribute__((ext_vector_type(8))) short;
using f32x4  = __attribute__((ext_vector_type(4))) float;
using float4v = __attribute__((ext_vector_type(4))) float;
using ushort4v = __attribute__((ext_vector_type(4))) unsigned short;

__device__ __forceinline__ unsigned short f2b(float f) {
    union { float f; unsigned int u; } v; v.f = f;
    unsigned int r = v.u + 0x7fffu + ((v.u >> 16) & 1u);
    return (unsigned short)(r >> 16);
}
__device__ __forceinline__ float b2f(unsigned short u) {
    union { unsigned int u; float f; } v; v.u = ((unsigned int)u) << 16;
    return v.f;
}
__device__ __forceinline__ ushort4v f2b4(float4v v) {
    ushort4v o;
    o.x = f2b(v.x); o.y = f2b(v.y); o.z = f2b(v.z); o.w = f2b(v.w);
    return o;
}

// ---------------------------------------------------------------------------
// Batched bf16 MFMA GEMM:  C[m,n] = sum_k X[m,k]*W[n,k] + bias[n]
// Tile 64x64, BK=64, 4 waves, dbuf LDS, global_load_lds staging (coalesced
// 64B 4-lane groups). Optional transposed bf16 dual-write via Ct/tr_row0.
// ---------------------------------------------------------------------------
struct GemmDesc {
    const unsigned short* X;
    const unsigned short* W;
    const float* bias;
    float* Cf;
    unsigned short* Cb;
    unsigned short* Ct;
    int M, N, K, ldX, ldC, tr_row0;
};
struct GemmArgs { GemmDesc d[4]; };

__global__ __launch_bounds__(256) void gemm_mfma(GemmArgs args)
{
    GemmDesc de = args.d[blockIdx.y];
    int tn = de.N >> 6;
    int tiles = (de.M >> 6) * tn;
    int t = blockIdx.x;
    if (t >= tiles) return;
    int m0 = (t / tn) << 6;
    int n0 = (t % tn) << 6;

    __shared__ unsigned short lsA[2][4096];
    __shared__ unsigned short lsB[2][4096];

    int tid = threadIdx.x;
    int w = tid >> 6;
    int l = tid & 63;
    int nkt = de.K >> 6;

    int srow = w * 16 + (l >> 2);
    int schk = l & 3;
    const unsigned short* gA = de.X + (size_t)(m0 + srow) * de.ldX + schk * 8;
    const unsigned short* gB = de.W + (size_t)(n0 + srow) * de.K  + schk * 8;
    unsigned short* lA = &lsA[0][(w * 64 + l) * 8];
    unsigned short* lB = &lsB[0][(w * 64 + l) * 8];

#define STAGE(bufi, kt)                                                          \
    do {                                                                         \
        __builtin_amdgcn_global_load_lds(                                        \
            (const __attribute__((address_space(1))) unsigned int*)(gA + (size_t)(kt) * 64), \
            (__attribute__((address_space(3))) unsigned int*)(lA + (bufi) * 4096), 16, 0, 0); \
        __builtin_amdgcn_global_load_lds(                                        \
            (const __attribute__((address_space(1))) unsigned int*)(gA + (size_t)(kt) * 64 + 32), \
            (__attribute__((address_space(3))) unsigned int*)(lA + (bufi) * 4096 + 2048), 16, 0, 0); \
        __builtin_amdgcn_global_load_lds(                                        \
            (const __attribute__((address_space(1))) unsigned int*)(gB + (size_t)(kt) * 64), \
            (__attribute__((address_space(3))) unsigned int*)(lB + (bufi) * 4096), 16, 0, 0); \
        __builtin_amdgcn_global_load_lds(                                        \
            (const __attribute__((address_space(1))) unsigned int*)(gB + (size_t)(kt) * 64 + 32), \
            (__attribute__((address_space(3))) unsigned int*)(lB + (bufi) * 4096 + 2048), 16, 0, 0); \
    } while (0)

    int mbase = (w >> 1) * 32;
    int nbase = (w & 1) * 32;

    f32x4 acc[2][2];
    #pragma unroll
    for (int i = 0; i < 2; ++i)
        #pragma unroll
        for (int j = 0; j < 2; ++j)
            acc[i][j] = (f32x4){0.f, 0.f, 0.f, 0.f};

    int kg = l >> 4;
    int fr = l & 15;
    int aslot = (mbase * 4 + fr * 4 + kg) * 8;
    int bslot = (nbase * 4 + fr * 4 + kg) * 8;

    STAGE(0, 0);

    for (int kt = 0; kt < nkt; ++kt) {
        __syncthreads();
        if (kt + 1 < nkt) STAGE((kt + 1) & 1, kt + 1);

        const unsigned short* bufA = &lsA[kt & 1][0];
        const unsigned short* bufB = &lsB[kt & 1][0];
        #pragma unroll
        for (int h = 0; h < 2; ++h) {
            bf16x8 a0 = *(const bf16x8*)(bufA + h * 2048 + aslot);
            bf16x8 a1 = *(const bf16x8*)(bufA + h * 2048 + aslot + 512);
            bf16x8 b0 = *(const bf16x8*)(bufB + h * 2048 + bslot);
            bf16x8 b1 = *(const bf16x8*)(bufB + h * 2048 + bslot + 512);
            acc[0][0] = __builtin_amdgcn_mfma_f32_16x16x32_bf16(a0, b0, acc[0][0], 0, 0, 0);
            acc[0][1] = __builtin_amdgcn_mfma_f32_16x16x32_bf16(a0, b1, acc[0][1], 0, 0, 0);
            acc[1][0] = __builtin_amdgcn_mfma_f32_16x16x32_bf16(a1, b0, acc[1][0], 0, 0, 0);
            acc[1][1] = __builtin_amdgcn_mfma_f32_16x16x32_bf16(a1, b1, acc[1][1], 0, 0, 0);
        }
    }

    #pragma unroll
    for (int mi = 0; mi < 2; ++mi) {
        #pragma unroll
        for (int ni = 0; ni < 2; ++ni) {
            int col = n0 + nbase + ni * 16 + fr;
            float bv = de.bias ? de.bias[col] : 0.f;
            #pragma unroll
            for (int r = 0; r < 4; ++r) {
                int row = m0 + mbase + mi * 16 + (l >> 4) * 4 + r;
                float v = acc[mi][ni][r] + bv;
                if (de.Cf) de.Cf[(size_t)row * de.ldC + col] = v;
                else       de.Cb[(size_t)row * de.ldC + col] = f2b(v);
                if (de.Ct && row >= de.tr_row0)
                    de.Ct[(size_t)col * 512 + (row - de.tr_row0)] = f2b(v);
            }
        }
    }
#undef STAGE
}

// ---------------------------------------------------------------------------
// Unified prep: 13 convert segments (flat index, ushort4 stores), 2 LDS
// transposes, bprime on 512 waves.  Grid 2688 x 256.
// Segment model (f4 units): r=i/dRL4, c=i%dRL4;
//   src = (c<half4) ? sA + (r*sRLA4+offA+c)*4 : sB + (r*sRLB4+c-half4)*4
// ---------------------------------------------------------------------------
#define NSEG 13
struct PrepArgs {
    const float* sA[NSEG]; const float* sB[NSEG]; unsigned short* dst[NSEG];
    int n4[NSEG], dRL4[NSEG], sRLA4[NSEG], sRLB4[NSEG], half4[NSEG], offA[NSEG];
    const float* A; unsigned short* ATb;
    const float* aout_w; unsigned short* aout_wT;
    const float* proj_w; const float* proj_b; const float* aout_b; float* bprime;
};
__global__ __launch_bounds__(256) void prep_kernel(PrepArgs a)
{
    __shared__ float tile[32][33];
    int bid = blockIdx.x, tid = threadIdx.x;
    if (bid < 2048) {
        const int gstride = 2048 * 256;
        int g0 = bid * 256 + tid;
        for (int seg = 0; seg < NSEG; ++seg) {
            int n4 = a.n4[seg];
            const float* sA = a.sA[seg];
            const float* sB = a.sB[seg];
            unsigned short* d = a.dst[seg];
            int dRL4 = a.dRL4[seg], sRLA4 = a.sRLA4[seg], sRLB4 = a.sRLB4[seg];
            int half4 = a.half4[seg], offA = a.offA[seg];
            for (int i = g0; i < n4; i += gstride) {
                int r = i / dRL4, c = i - r * dRL4;
                const float* src = (c < half4)
                    ? sA + ((size_t)r * sRLA4 + offA + c) * 4
                    : sB + ((size_t)r * sRLB4 + (c - half4)) * 4;
                float4v v = *(const float4v*)src;
                *(ushort4v*)(d + (size_t)i * 4) = f2b4(v);
            }
        }
    } else if (bid < 2560) {
        int t = bid - 2048;
        const float* src = (t < 256) ? a.A : a.aout_w;
        unsigned short* dst = (t < 256) ? a.ATb : a.aout_wT;
        int tt = t & 255;
        int bx = tt & 15, by = tt >> 4;
        int tx = tid & 31, ty = tid >> 5;
        #pragma unroll
        for (int i = 0; i < 32; i += 8)
            tile[ty + i][tx] = src[(size_t)(by * 32 + ty + i) * 512 + bx * 32 + tx];
        __syncthreads();
        #pragma unroll
        for (int i = 0; i < 32; i += 8)
            dst[(size_t)(bx * 32 + ty + i) * 512 + by * 32 + tx] = f2b(tile[tx][ty + i]);
    } else {
        // bprime: 128 blocks x 4 waves = 512 waves, one row each
        int i = (bid - 2560) * 4 + (tid >> 6);
        int lane = tid & 63;
        float acc = 0.f;
        #pragma unroll
        for (int n = 0; n < 512; n += 64)
            acc += a.proj_w[(size_t)i * 2560 + 512 + n + lane] * a.aout_b[n + lane];
        #pragma unroll
        for (int off = 32; off > 0; off >>= 1) acc += __shfl_down(acc, off);
        if (lane == 0) a.bprime[i] = a.proj_b[i] + acc;
    }
}

// ---------------------------------------------------------------------------
__device__ __forceinline__ void block_reduce2(float& s, float& q, float* sb1, float* sb2)
{
    int tid = threadIdx.x;
    #pragma unroll
    for (int off = 32; off > 0; off >>= 1) {
        s += __shfl_down(s, off);
        q += __shfl_down(q, off);
    }
    if ((tid & 63) == 0) { sb1[tid >> 6] = s; sb2[tid >> 6] = q; }
    __syncthreads();
    s = sb1[0] + sb1[1] + sb1[2] + sb1[3];
    q = sb2[0] + sb2[1] + sb2[2] + sb2[3];
    __syncthreads();
}

__global__ __launch_bounds__(256) void ln_gelu_delta(
    const float* __restrict__ pre, const float* __restrict__ g,
    const float* __restrict__ beta, const float* __restrict__ w2,
    const float* __restrict__ b2, float* __restrict__ delta,
    float* __restrict__ coeff)
{
    __shared__ float sb1[4], sb2[4];
    int b = blockIdx.x, tid = threadIdx.x;
    int i0 = tid, i1 = tid + 256;
    float x0 = pre[(size_t)b * DIM + i0];
    float x1 = pre[(size_t)b * DIM + i1];
    float s = x0 + x1, q = x0 * x0 + x1 * x1;
    block_reduce2(s, q, sb1, sb2);
    float mean = s * (1.f / DIM);
    float var  = q * (1.f / DIM) - mean * mean;
    float inv  = rsqrtf(var + 1e-5f);
    float y0 = (x0 - mean) * inv * g[i0] + beta[i0];
    float y1 = (x1 - mean) * inv * g[i1] + beta[i1];
    float h0 = 0.5f * y0 * (1.f + erff(y0 * 0.70710678118654752f));
    float h1 = 0.5f * y1 * (1.f + erff(y1 * 0.70710678118654752f));
    float p = h0 * w2[i0] + h1 * w2[i1];
    float dummy = 0.f;
    block_reduce2(p, dummy, sb1, sb2);
    if (tid == 0) {
        float z = p + b2[0];
        float d = (z > 20.f) ? z : log1pf(expf(z));
        delta[b] = d;
        float c = 1.f;
        coeff[b] = 1.f;
        for (int k = 1; k <= KMAX; ++k) { c *= d / (float)k; coeff[k * 256 + b] = c; }
    }
}

// ---------------------------------------------------------------------------
// Fused pointwise, vectorized x4: Taylor accum (idx4 < 32768) + LSTM cell.
// ---------------------------------------------------------------------------
__global__ void pointwise_fused(
    const float* __restrict__ Tm, const float* __restrict__ coeff,
    const float* __restrict__ h_prev, const float* __restrict__ delta,
    const float* __restrict__ Bx, float* __restrict__ hssm,
    unsigned short* __restrict__ combb,
    const float* __restrict__ gates, const float* __restrict__ bih,
    const float* __restrict__ bhh, const float* __restrict__ cin,
    const float* __restrict__ decays,
    float* __restrict__ hout, float* __restrict__ cout)
{
    int idx4 = blockIdx.x * 256 + threadIdx.x;   // 0..131071
    int base = idx4 * 4;
    if (base < 131072) {
        int b = base >> 9, i = base & 511;
        const float* Tr = Tm + (size_t)b * (KMAX * DIM) + i;
        float4v a = *(const float4v*)(h_prev + base);
        #pragma unroll
        for (int k = 1; k <= KMAX; ++k) {
            float c = coeff[k * 256 + b];
            float4v t = *(const float4v*)(Tr + (size_t)(k - 1) * DIM);
            a.x += c * t.x; a.y += c * t.y; a.z += c * t.z; a.w += c * t.w;
        }
        float dl = delta[b];
        float4v bx = *(const float4v*)(Bx + base);
        a.x += dl * bx.x; a.y += dl * bx.y; a.z += dl * bx.z; a.w += dl * bx.w;
        *(float4v*)(hssm + base) = a;
        *(ushort4v*)(combb + (size_t)b * 2560 + i) = f2b4(a);
    } else {
        int i2 = base - 131072;                  // 0..393212, multiple of 4
        int s = i2 / (NB * DIM);
        int r = i2 - s * (NB * DIM);
        int b = r >> 9, d = r & 511;
        const float* gr = gates + (size_t)s * 524288 + (size_t)b * 2048 + d;
        const float* bi = bih + s * 2048 + d;
        const float* bh = bhh + s * 2048 + d;
        float4v gi = *(const float4v*)(gr);
        float4v gf = *(const float4v*)(gr + 512);
        float4v gg = *(const float4v*)(gr + 1024);
        float4v go = *(const float4v*)(gr + 1536);
        float4v bi0 = *(const float4v*)(bi),       bh0 = *(const float4v*)(bh);
        float4v bi1 = *(const float4v*)(bi + 512), bh1 = *(const float4v*)(bh + 512);
        float4v bi2 = *(const float4v*)(bi + 1024),bh2 = *(const float4v*)(bh + 1024);
        float4v bi3 = *(const float4v*)(bi + 1536),bh3 = *(const float4v*)(bh + 1536);
        float4v c = *(const float4v*)(cin + i2);
        float dec = decays[s];
        float4v hn, cn;
        #pragma unroll
        for (int j = 0; j < 4; ++j) {
            float vgi = ((const float*)&gi)[j] + ((const float*)&bi0)[j] + ((const float*)&bh0)[j];
            float vgf = ((const float*)&gf)[j] + ((const float*)&bi1)[j] + ((const float*)&bh1)[j];
            float vgg = ((const float*)&gg)[j] + ((const float*)&bi2)[j] + ((const float*)&bh2)[j];
            float vgo = ((const float*)&go)[j] + ((const float*)&bi3)[j] + ((const float*)&bh3)[j];
            float ig = 1.f / (1.f + expf(-vgi));
            float fg = 1.f / (1.f + expf(-vgf));
            float g_ = tanhf(vgg);
            float og = 1.f / (1.f + expf(-vgo));
            float cc = ((const float*)&c)[j];
            float craw = fg * cc + ig * g_;
            ((float*)&hn)[j] = og * tanhf(craw);
            ((float*)&cn)[j] = dec * cc + (1.f - dec) * craw;
        }
        *(float4v*)(hout + i2) = hn;
        *(float4v*)(cout + i2) = cn;
        *(ushort4v*)(combb + (size_t)b * 2560 + 1024 + s * 512 + d) = f2b4(hn);
    }
}

// ---------------------------------------------------------------------------
// Attention, vectorized: 256 blocks (b) x 128 threads; thread t: h=t>>4,
// 4 elems at (t&15)*4. 16-lane shuffle reduction.  ctx -> combb cols 512..1023.
// ---------------------------------------------------------------------------
__global__ __launch_bounds__(128) void attn_kernel(
    const unsigned short* __restrict__ qb, const unsigned short* __restrict__ kvb,
    unsigned short* __restrict__ combb)
{
    int b = blockIdx.x, t = threadIdx.x;
    int h = t >> 4, sub = (t & 15) * 4;
    int col = h * 64 + sub;
    ushort4v q4 = *(const ushort4v*)(qb + (size_t)b * 512 + col);
    float qf[4] = { b2f(q4.x), b2f(q4.y), b2f(q4.z), b2f(q4.w) };
    float p[3];
    ushort4v k4[3], v4[3];
    #pragma unroll
    for (int s = 0; s < 3; ++s) {
        k4[s] = *(const ushort4v*)(kvb + (size_t)s * 262144 + (size_t)b * 1024 + col);
        v4[s] = *(const ushort4v*)(kvb + (size_t)s * 262144 + (size_t)b * 1024 + 512 + col);
        p[s] = qf[0] * b2f(k4[s].x) + qf[1] * b2f(k4[s].y)
             + qf[2] * b2f(k4[s].z) + qf[3] * b2f(k4[s].w);
    }
    #pragma unroll
    for (int off = 1; off < 16; off <<= 1) {
        p[0] += __shfl_xor(p[0], off);
        p[1] += __shfl_xor(p[1], off);
        p[2] += __shfl_xor(p[2], off);
    }
    const float scale = 0.125f;
    float p0 = p[0] * scale, p1 = p[1] * scale, p2 = p[2] * scale;
    float m = fmaxf(p0, fmaxf(p1, p2));
    float w0 = expf(p0 - m), w1 = expf(p1 - m), w2 = expf(p2 - m);
    float invs = 1.f / (w0 + w1 + w2);
    float4v ctx;
    ((float*)&ctx)[0] = (w0 * b2f(v4[0].x) + w1 * b2f(v4[1].x) + w2 * b2f(v4[2].x)) * invs;
    ((float*)&ctx)[1] = (w0 * b2f(v4[0].y) + w1 * b2f(v4[1].y) + w2 * b2f(v4[2].y)) * invs;
    ((float*)&ctx)[2] = (w0 * b2f(v4[0].z) + w1 * b2f(v4[1].z) + w2 * b2f(v4[2].z)) * invs;
    ((float*)&ctx)[3] = (w0 * b2f(v4[0].w) + w1 * b2f(v4[1].w) + w2 * b2f(v4[2].w)) * invs;
    *(ushort4v*)(combb + (size_t)b * 2560 + 512 + col) = f2b4(ctx);
}

// ---------------------------------------------------------------------------
__global__ __launch_bounds__(256) void layernorm_k(
    const float* __restrict__ in, const float* __restrict__ g,
    const float* __restrict__ beta, float* __restrict__ outp)
{
    __shared__ float sb1[4], sb2[4];
    int b = blockIdx.x, tid = threadIdx.x;
    int i0 = tid, i1 = tid + 256;
    float x0 = in[(size_t)b * DIM + i0];
    float x1 = in[(size_t)b * DIM + i1];
    float s = x0 + x1, q = x0 * x0 + x1 * x1;
    block_reduce2(s, q, sb1, sb2);
    float mean = s * (1.f / DIM);
    float var  = q * (1.f / DIM) - mean * mean;
    float inv  = rsqrtf(var + 1e-5f);
    outp[(size_t)b * DIM + i0] = (x0 - mean) * inv * g[i0] + beta[i0];
    outp[(size_t)b * DIM + i1] = (x1 - mean) * inv * g[i1] + beta[i1];
}

// ---------------------------------------------------------------------------
extern "C" void kernel_launch(void* const* d_in, const int* in_sizes, int n_in,
                              void* d_out, int out_size, void* d_ws, size_t ws_size,
                              hipStream_t stream)
{
    const float* x        = (const float*)d_in[0];
    const float* h_prev   = (const float*)d_in[1];
    const float* lstm_h   = (const float*)d_in[2];
    const float* lstm_c   = (const float*)d_in[3];
    const float* A        = (const float*)d_in[4];
    const float* Bm       = (const float*)d_in[5];
    const float* dn_w1    = (const float*)d_in[6];
    const float* dn_b1    = (const float*)d_in[7];
    const float* dn_g     = (const float*)d_in[8];
    const float* dn_beta  = (const float*)d_in[9];
    const float* dn_w2    = (const float*)d_in[10];
    const float* dn_b2    = (const float*)d_in[11];
    const float* wih      = (const float*)d_in[12];
    const float* whh      = (const float*)d_in[13];
    const float* bih      = (const float*)d_in[14];
    const float* bhh      = (const float*)d_in[15];
    const float* decays   = (const float*)d_in[16];
    const float* ain_w    = (const float*)d_in[17];
    const float* ain_b    = (const float*)d_in[18];
    const float* aout_w   = (const float*)d_in[19];
    const float* aout_b   = (const float*)d_in[20];
    const float* proj_w   = (const float*)d_in[21];
    const float* proj_b   = (const float*)d_in[22];
    const float* proj_g   = (const float*)d_in[23];
    const float* proj_bt  = (const float*)d_in[24];

    float* out  = (float*)d_out;
    float* hssm = out + 131072;
    float* hnew = out + 262144;
    float* cnew = out + 655360;

    // ---- workspace (bf16 section) ----
    unsigned short* us = (unsigned short*)d_ws;
    unsigned short* hpb     = us;                  // 131072
    unsigned short* ATb     = us + 131072;         // 262144
    unsigned short* dn_w1b  = us + 393216;         // 262144
    unsigned short* Bmb     = us + 655360;         // 262144
    unsigned short* ain_wb  = us + 917504;         // 786432
    unsigned short* proj_wb = us + 1703936;        // 1310720 (512 x 2560)
    unsigned short* P2b     = us + 3014656;        // 262144
    unsigned short* aout_wT = us + 3276800;        // 262144
    unsigned short* Pw      = us + 3538944;        // 16*262144 [A^1..A^16]
    unsigned short* Qa      = us + 7733248;        // 262144
    unsigned short* Qb      = us + 7995392;        // 262144
    unsigned short* Wcat    = us + 8257536;        // 6291456
    unsigned short* Xcat    = us + 14548992;       // 786432
    unsigned short* combb   = us + 15335424;       // 655360 (256 x 2560)
    unsigned short* qb      = us + 15990784;       // 131072
    unsigned short* kvb     = us + 16121856;       // 786432
    // ---- fp32 section ----
    float* fbase  = (float*)(us + 16908288);
    float* pre1   = fbase;                         // 131072 (reused as projout)
    float* delta  = fbase + 131072;                // 256
    float* coeff  = fbase + 131328;                // 17*256
    float* Bx     = fbase + 135680;                // 131072
    float* bprime = fbase + 266752;                // 512
    float* Tm     = fbase + 267264;                // 256*8192
    float* gates  = fbase + 2364416;               // 1572864
    float* projout = pre1;

    // ---- 1. unified prep (13 segments + transposes + bprime) ----
    PrepArgs pa;
    int sidx = 0;
    auto LIN = [&](const float* s, unsigned short* d, int n4) {
        pa.sA[sidx]=s; pa.sB[sidx]=s; pa.dst[sidx]=d; pa.n4[sidx]=n4;
        pa.dRL4[sidx]=n4; pa.sRLA4[sidx]=0; pa.sRLB4[sidx]=0;
        pa.half4[sidx]=n4; pa.offA[sidx]=0; ++sidx;
    };
    LIN(h_prev, hpb,     32768);
    LIN(A,      Pw,      65536);
    LIN(dn_w1,  dn_w1b,  65536);
    LIN(Bm,     Bmb,     65536);
    LIN(ain_w,  ain_wb,  196608);
    LIN(proj_w, proj_wb, 327680);
    // P2b: proj_w cols 512..1023 -> 512x512
    pa.sA[sidx]=proj_w; pa.sB[sidx]=proj_w; pa.dst[sidx]=P2b; pa.n4[sidx]=65536;
    pa.dRL4[sidx]=128; pa.sRLA4[sidx]=640; pa.sRLB4[sidx]=640; pa.half4[sidx]=128; pa.offA[sidx]=128; ++sidx;
    // Wcat_s = [wih_s | whh_s]
    for (int s = 0; s < 3; ++s) {
        pa.sA[sidx]=wih + (size_t)s*1048576; pa.sB[sidx]=whh + (size_t)s*1048576;
        pa.dst[sidx]=Wcat + (size_t)s*2097152; pa.n4[sidx]=524288;
        pa.dRL4[sidx]=256; pa.sRLA4[sidx]=128; pa.sRLB4[sidx]=128; pa.half4[sidx]=128; pa.offA[sidx]=0; ++sidx;
    }
    // Xcat_s = [x | lstm_h_s]
    for (int s = 0; s < 3; ++s) {
        pa.sA[sidx]=x; pa.sB[sidx]=lstm_h + (size_t)s*131072;
        pa.dst[sidx]=Xcat + (size_t)s*262144; pa.n4[sidx]=65536;
        pa.dRL4[sidx]=256; pa.sRLA4[sidx]=128; pa.sRLB4[sidx]=128; pa.half4[sidx]=128; pa.offA[sidx]=0; ++sidx;
    }
    pa.A = A; pa.ATb = ATb; pa.aout_w = aout_w; pa.aout_wT = aout_wT;
    pa.proj_w = proj_w; pa.proj_b = proj_b; pa.aout_b = aout_b; pa.bprime = bprime;
    prep_kernel<<<2688, 256, 0, stream>>>(pa);

    GemmArgs ga;
    // ---- 2. batch1: dense1, Bx, M2 = P2.aout_w, G1 (A^2 + Q2) ----
    ga.d[0] = { Xcat, dn_w1b, dn_b1, pre1, nullptr, nullptr, 256, 512, 512, 1024, 512, 0 };
    ga.d[1] = { Xcat, Bmb,    nullptr, Bx,  nullptr, nullptr, 256, 512, 512, 1024, 512, 0 };
    ga.d[2] = { P2b,  aout_wT, nullptr, nullptr, proj_wb + 512, nullptr, 512, 512, 512, 512, 2560, 0 };
    ga.d[3] = { Pw, ATb, nullptr, nullptr, Pw + 1*262144, Qa, 512, 512, 512, 512, 512, 0 };
    gemm_mfma<<<dim3(64, 4), 256, 0, stream>>>(ga);
    ln_gelu_delta<<<256, 256, 0, stream>>>(pre1, dn_g, dn_beta, dn_w2, dn_b2, delta, coeff);

    // ---- 3. power chain: [A^3,A^4]; [A^5..A^8]; [A^9..A^16] ----
    ga.d[0] = { Pw, Qa, nullptr, nullptr, Pw + 2*262144, Qb, 1024, 512, 512, 512, 512, 512 };
    gemm_mfma<<<dim3(128, 1), 256, 0, stream>>>(ga);
    ga.d[0] = { Pw, Qb, nullptr, nullptr, Pw + 4*262144, Qa, 2048, 512, 512, 512, 512, 1536 };
    gemm_mfma<<<dim3(256, 1), 256, 0, stream>>>(ga);
    ga.d[0] = { Pw, Qa, nullptr, nullptr, Pw + 8*262144, nullptr, 4096, 512, 512, 512, 512, 0 };
    gemm_mfma<<<dim3(512, 1), 256, 0, stream>>>(ga);

    // ---- 4. batch2: Taylor (N=8192) + LSTM x3 ----
    ga.d[0] = { hpb, Pw, nullptr, Tm, nullptr, nullptr, 256, KMAX*512, 512, 512, KMAX*512, 0 };
    for (int s = 0; s < 3; ++s)
        ga.d[1 + s] = { Xcat + (size_t)s * 262144, Wcat + (size_t)s * 2097152, nullptr,
                        gates + (size_t)s * 524288, nullptr, nullptr, 256, 2048, 1024, 1024, 2048, 0 };
    gemm_mfma<<<dim3(512, 4), 256, 0, stream>>>(ga);

    // ---- 5. fused pointwise ----
    pointwise_fused<<<512, 256, 0, stream>>>(Tm, coeff, h_prev, delta, Bx, hssm, combb,
                                             gates, bih, bhh, lstm_c, decays, hnew, cnew);

    // ---- 6. attention qkv + softmax ----
    ga.d[0] = { combb, ain_wb, ain_b, nullptr, qb, nullptr, 256, 512, 512, 2560, 512, 0 };
    for (int s = 0; s < 3; ++s)
        ga.d[1 + s] = { combb + 1024 + (size_t)s * 512, ain_wb + 262144, ain_b + 512,
                        nullptr, kvb + (size_t)s * 262144, nullptr, 256, 1024, 512, 2560, 1024, 0 };
    gemm_mfma<<<dim3(64, 4), 256, 0, stream>>>(ga);
    attn_kernel<<<256, 128, 0, stream>>>(qb, kvb, combb);

    // ---- 7. projection (M2-fused, bias=bprime) + final LN ----
    ga.d[0] = { combb, proj_wb, bprime, projout, nullptr, nullptr, 256, 512, 2560, 2560, 512, 0 };
    gemm_mfma<<<dim3(32, 1), 256, 0, stream>>>(ga);
    layernorm_k<<<256, 256, 0, stream>>>(projout, proj_g, proj_bt, out);
}